// Round 1
// baseline (3591.982 us; speedup 1.0000x reference)
//
#include <hip/hip_runtime.h>
#include <math.h>

// Problem constants
#define NB    1024      // batch rows == scan steps
#define SEQ   600
#define EDIM  300
#define HDIM  256
#define DIN   903       // 3*E + 3
#define GDIM  1024      // 4*H

// ---------------------------------------------------------------------------
// Kernel 1: conv — per row: 3 segment means of gathered embeddings + 3 cosines
// (unchanged)
// ---------------------------------------------------------------------------
__global__ __launch_bounds__(256) void conv_kernel(const int* __restrict__ x,
                                                   const float* __restrict__ emb,
                                                   float* __restrict__ X) {
    const int row = blockIdx.x;
    const int tid = threadIdx.x;
    const int* xr = x + (size_t)row * SEQ;

    __shared__ float seg[3][EDIM];
    __shared__ float scnt[3];
    __shared__ float reds[6];
    __shared__ float coss[3];

    if (tid < 6) reds[tid] = 0.f;
    if (tid < 3) scnt[tid] = 0.f;
    __syncthreads();

    {
        int c0 = 0, c1 = 0, c2 = 0;
        for (int t = tid; t < 200; t += 256) {
            c0 += (xr[t]       != 0);
            c1 += (xr[200 + t] != 0);
            c2 += (xr[400 + t] != 0);
        }
        float f0 = (float)c0, f1 = (float)c1, f2 = (float)c2;
        #pragma unroll
        for (int m = 1; m < 64; m <<= 1) {
            f0 += __shfl_xor(f0, m);
            f1 += __shfl_xor(f1, m);
            f2 += __shfl_xor(f2, m);
        }
        if ((tid & 63) == 0) {
            atomicAdd(&scnt[0], f0);
            atomicAdd(&scnt[1], f1);
            atomicAdd(&scnt[2], f2);
        }
    }
    __syncthreads();

    const float inv0 = 1.f / scnt[0], inv1 = 1.f / scnt[1], inv2 = 1.f / scnt[2];

    for (int d = tid; d < EDIM; d += 256) {
        float a0 = 0.f, a1 = 0.f, a2 = 0.f;
        for (int t = 0; t < 200; t++) {
            a0 += emb[(size_t)xr[t]       * EDIM + d];
            a1 += emb[(size_t)xr[200 + t] * EDIM + d];
            a2 += emb[(size_t)xr[400 + t] * EDIM + d];
        }
        seg[0][d] = a0 * inv0;
        seg[1][d] = a1 * inv1;
        seg[2][d] = a2 * inv2;
    }
    __syncthreads();

    {
        float p0 = 0, p1 = 0, p2 = 0, p3 = 0, p4 = 0, p5 = 0;
        for (int d = tid; d < EDIM; d += 256) {
            float a = seg[0][d], b = seg[1][d], c = seg[2][d];
            p0 += a * a; p1 += b * b; p2 += c * c;
            p3 += a * b; p4 += b * c; p5 += a * c;
        }
        #pragma unroll
        for (int m = 1; m < 64; m <<= 1) {
            p0 += __shfl_xor(p0, m); p1 += __shfl_xor(p1, m);
            p2 += __shfl_xor(p2, m); p3 += __shfl_xor(p3, m);
            p4 += __shfl_xor(p4, m); p5 += __shfl_xor(p5, m);
        }
        if ((tid & 63) == 0) {
            atomicAdd(&reds[0], p0); atomicAdd(&reds[1], p1);
            atomicAdd(&reds[2], p2); atomicAdd(&reds[3], p3);
            atomicAdd(&reds[4], p4); atomicAdd(&reds[5], p5);
        }
    }
    __syncthreads();
    if (tid == 0) {
        float nt = fmaxf(sqrtf(reds[0]), 1e-8f);
        float nu = fmaxf(sqrtf(reds[1]), 1e-8f);
        float nj = fmaxf(sqrtf(reds[2]), 1e-8f);
        coss[0] = reds[3] / (nt * nu);
        coss[1] = reds[4] / (nu * nj);
        coss[2] = reds[5] / (nt * nj);
    }
    __syncthreads();

    float* Xr = X + (size_t)row * DIN;
    for (int col = tid; col < DIN; col += 256) {
        float v;
        if      (col < 300)  v = seg[0][col];
        else if (col == 300) v = coss[0];
        else if (col < 601)  v = seg[1][col - 301];
        else if (col == 601) v = coss[1];
        else if (col < 902)  v = seg[2][col - 602];
        else                 v = coss[2];
        Xr[col] = v;
    }
}

// ---------------------------------------------------------------------------
// Kernel 2: GEMM  C[1024][1024] = A[1024][K] * B[1024][K]^T + bias1 + bias2
// (unchanged)
// ---------------------------------------------------------------------------
__global__ __launch_bounds__(256) void gemm_bias(const float* __restrict__ A,
                                                 const float* __restrict__ Bm,
                                                 const float* __restrict__ bias1,
                                                 const float* __restrict__ bias2,
                                                 float* __restrict__ C, int K) {
    __shared__ float As[16][68];
    __shared__ float Bs[16][68];
    const int tid = threadIdx.x;
    const int tx = tid & 15, ty = tid >> 4;
    const int m0 = blockIdx.y * 64, n0 = blockIdx.x * 64;

    float acc[4][4] = {};
    for (int k0 = 0; k0 < K; k0 += 16) {
        #pragma unroll
        for (int i = 0; i < 4; i++) {
            int e  = tid + i * 256;
            int rr = e >> 4, kk = e & 15;
            int k  = k0 + kk;
            As[kk][rr] = (k < K) ? A[(size_t)(m0 + rr) * K + k] : 0.f;
            Bs[kk][rr] = (k < K) ? Bm[(size_t)(n0 + rr) * K + k] : 0.f;
        }
        __syncthreads();
        #pragma unroll
        for (int kk = 0; kk < 16; kk++) {
            float a[4], b[4];
            #pragma unroll
            for (int i = 0; i < 4; i++) { a[i] = As[kk][ty * 4 + i]; b[i] = Bs[kk][tx * 4 + i]; }
            #pragma unroll
            for (int i = 0; i < 4; i++)
                #pragma unroll
                for (int j = 0; j < 4; j++)
                    acc[i][j] += a[i] * b[j];
        }
        __syncthreads();
    }
    #pragma unroll
    for (int i = 0; i < 4; i++) {
        int m = m0 + ty * 4 + i;
        #pragma unroll
        for (int j = 0; j < 4; j++) {
            int n = n0 + tx * 4 + j;
            C[(size_t)m * GDIM + n] = acc[i][j] + bias1[n] + bias2[n];
        }
    }
}

// ---------------------------------------------------------------------------
// Kernel 3: fused 2-layer sequential LSTM — wave-autonomous version.
// 256 WGs x 64 threads = 256 independent waves (128 per layer).
// Wave W of layer L owns h-elements {2W, 2W+1}: 8 gate rows x 8 lanes/row.
//   lane l: s = l>>5 (element), g = (l>>3)&3 (gate i/f/g/o), q = l&7 (col chunk)
//   row = g*256 + 2W + s ; lane covers cols {q + 8j, j=0..31} (interleaved).
// Per step: each lane polls h[l], h[64+l], h[128+l], h[192+l] from the global
// mailbox (write-once rows pre-filled 0xFFFFFFFF = NaN, agent-scope relaxed
// atomics — same protocol as before), redistributes in-register via __shfl
// (col c -> reg c>>6 uniform, src lane c&63), 3-step shfl_xor butterfly over
// q, 4-shuffle gate gather, then ALL lanes compute the nonlinearity
// redundantly (c replicated per-lane). Lanes 0/32 publish h.
// No __syncthreads, no LDS arrays, no wave0-serial phase.
// ---------------------------------------------------------------------------
__global__ __launch_bounds__(64) void lstm_fused(
    const float* __restrict__ G1,
    const float* __restrict__ Whh0,
    const float* __restrict__ Wih1,
    const float* __restrict__ Whh1,
    const float* __restrict__ b_ih1,
    const float* __restrict__ b_hh1,
    const float* __restrict__ h0,
    const float* __restrict__ c0,
    float* ys1, float* ys2,
    float* out)
{
    const int  l    = threadIdx.x & 63;
    const int  bx   = blockIdx.x;
    const bool isL2 = bx >= 128;
    const int  L    = isL2 ? 1 : 0;
    const int  W    = bx & 127;          // wave index within layer, 0..127
    const int  s    = l >> 5;
    const int  g    = (l >> 3) & 3;
    const int  q    = l & 7;
    const int  elem = 2 * W + s;         // 0..255
    const int  row  = g * 256 + elem;    // gate row 0..1023

    // per-lane weight slices, interleaved columns: w[j] = W[row][q + 8j]
    float whh[32];
    float wih[32] = {};
    {
        const float* Wh = isL2 ? Whh1 : Whh0;
        #pragma unroll
        for (int j = 0; j < 32; j++)
            whh[j] = Wh[(size_t)row * HDIM + q + 8 * j];
    }
    if (isL2) {
        #pragma unroll
        for (int j = 0; j < 32; j++)
            wih[j] = Wih1[(size_t)row * HDIM + q + 8 * j];
    }
    const float bias = isL2 ? (b_ih1[row] + b_hh1[row]) : 0.f;

    float c = c0[L * HDIM + elem];       // replicated across the element's lanes

    const float* ysIn  = isL2 ? ys2 : ys1;   // own-layer h mailbox
    float*       ysOut = isL2 ? ys2 : ys1;
    const float* Grow  = G1 + row;

    for (int t = 0; t < NB; t++) {
        // x-gate contribution for this lane's row (L1: precomputed GEMM; L2: bias)
        float gval = isL2 ? bias : Grow[(size_t)t * GDIM];

        // ---- own-layer h(t-1): 4 dwords per lane, stride-64 (coalesced) ----
        float hreg[4];
        if (t == 0) {
            #pragma unroll
            for (int r = 0; r < 4; r++) hreg[r] = h0[L * HDIM + 64 * r + l];
        } else {
            const unsigned* p = (const unsigned*)(ysIn + (size_t)(t - 1) * HDIM) + l;
            unsigned a0, a1, a2, a3; int gd = 0;
            do {
                a0 = __hip_atomic_load(p      , __ATOMIC_RELAXED, __HIP_MEMORY_SCOPE_AGENT);
                a1 = __hip_atomic_load(p +  64, __ATOMIC_RELAXED, __HIP_MEMORY_SCOPE_AGENT);
                a2 = __hip_atomic_load(p + 128, __ATOMIC_RELAXED, __HIP_MEMORY_SCOPE_AGENT);
                a3 = __hip_atomic_load(p + 192, __ATOMIC_RELAXED, __HIP_MEMORY_SCOPE_AGENT);
            } while (((a0 == 0xFFFFFFFFu) | (a1 == 0xFFFFFFFFu) |
                      (a2 == 0xFFFFFFFFu) | (a3 == 0xFFFFFFFFu)) && ++gd < (1 << 24));
            hreg[0] = __uint_as_float(a0); hreg[1] = __uint_as_float(a1);
            hreg[2] = __uint_as_float(a2); hreg[3] = __uint_as_float(a3);
        }

        // ---- L2: x input ys1[t] (produced by L1 at its step t) ----
        float xreg[4] = {};
        if (isL2) {
            const unsigned* p = (const unsigned*)(ys1 + (size_t)t * HDIM) + l;
            unsigned a0, a1, a2, a3; int gd = 0;
            do {
                a0 = __hip_atomic_load(p      , __ATOMIC_RELAXED, __HIP_MEMORY_SCOPE_AGENT);
                a1 = __hip_atomic_load(p +  64, __ATOMIC_RELAXED, __HIP_MEMORY_SCOPE_AGENT);
                a2 = __hip_atomic_load(p + 128, __ATOMIC_RELAXED, __HIP_MEMORY_SCOPE_AGENT);
                a3 = __hip_atomic_load(p + 192, __ATOMIC_RELAXED, __HIP_MEMORY_SCOPE_AGENT);
            } while (((a0 == 0xFFFFFFFFu) | (a1 == 0xFFFFFFFFu) |
                      (a2 == 0xFFFFFFFFu) | (a3 == 0xFFFFFFFFu)) && ++gd < (1 << 24));
            xreg[0] = __uint_as_float(a0); xreg[1] = __uint_as_float(a1);
            xreg[2] = __uint_as_float(a2); xreg[3] = __uint_as_float(a3);
        }

        // ---- matvec: col c = q + 8j; value lives in reg c>>6 of lane c&63 ----
        float acc = 0.f;
        #pragma unroll
        for (int j = 0; j < 32; j++)
            acc += whh[j] * __shfl(hreg[j >> 3], q + 8 * (j & 7));
        if (isL2) {
            #pragma unroll
            for (int j = 0; j < 32; j++)
                acc += wih[j] * __shfl(xreg[j >> 3], q + 8 * (j & 7));
        }
        if (q == 0) acc += gval;          // added once per row (butterfly sums it in)
        acc += __shfl_xor(acc, 1);
        acc += __shfl_xor(acc, 2);
        acc += __shfl_xor(acc, 4);        // now every lane holds its row's full gate

        // ---- gather the 4 gates of this lane's element ----
        const int hi = l & 32;
        float gi = __shfl(acc, hi);
        float gf = __shfl(acc, hi + 8);
        float gg = __shfl(acc, hi + 16);
        float go = __shfl(acc, hi + 24);

        // ---- nonlinearity + state update (all lanes, redundant = free) ----
        float ig = 1.f / (1.f + expf(-gi));
        float fg = 1.f / (1.f + expf(-gf));
        float og = 1.f / (1.f + expf(-go));
        c = fg * c + ig * tanhf(gg);
        float h = og * tanhf(c);

        // ---- publish (one lane per element) ----
        if ((l & 31) == 0) {
            __hip_atomic_store(&ysOut[(size_t)t * HDIM + elem], h,
                               __ATOMIC_RELAXED, __HIP_MEMORY_SCOPE_AGENT);
            if (t == NB - 1) {
                out[1024 + L * HDIM + elem] = h;   // hn
                out[1536 + L * HDIM + elem] = c;   // cn
            }
        }
    }
}

// ---------------------------------------------------------------------------
// Kernel 4: fc head (unchanged)
// ---------------------------------------------------------------------------
__global__ __launch_bounds__(256) void fc_kernel(const float* __restrict__ ys2,
                                                 const float* __restrict__ fc_w,
                                                 const float* __restrict__ fc_b,
                                                 float* __restrict__ out) {
    const int row  = blockIdx.x * 4 + (threadIdx.x >> 6);
    const int lane = threadIdx.x & 63;
    float4 y = ((const float4*)(ys2 + (size_t)row * HDIM))[lane];
    float4 wv = ((const float4*)fc_w)[lane];
    float d = y.x * wv.x + y.y * wv.y + y.z * wv.z + y.w * wv.w;
    #pragma unroll
    for (int m = 1; m < 64; m <<= 1) d += __shfl_xor(d, m);
    if (lane == 0) out[row] = 1.f / (1.f + expf(-(d + fc_b[0])));
}

// ---------------------------------------------------------------------------
extern "C" void kernel_launch(void* const* d_in, const int* in_sizes, int n_in,
                              void* d_out, int out_size, void* d_ws, size_t ws_size,
                              hipStream_t stream) {
    const int*   x     = (const int*)  d_in[0];
    const float* h0    = (const float*)d_in[1];
    const float* c0    = (const float*)d_in[2];
    const float* emb   = (const float*)d_in[3];
    const float* w_ih0 = (const float*)d_in[4];
    const float* w_hh0 = (const float*)d_in[5];
    const float* b_ih0 = (const float*)d_in[6];
    const float* b_hh0 = (const float*)d_in[7];
    const float* w_ih1 = (const float*)d_in[8];
    const float* w_hh1 = (const float*)d_in[9];
    const float* b_ih1 = (const float*)d_in[10];
    const float* b_hh1 = (const float*)d_in[11];
    const float* fc_w  = (const float*)d_in[12];
    const float* fc_b  = (const float*)d_in[13];
    float* out = (float*)d_out;

    // workspace layout (floats)
    float* X   = (float*)d_ws;                  // 1024*903
    float* G1  = X + (size_t)NB * DIN;          // 1024*1024
    float* ys1 = G1 + (size_t)NB * GDIM;        // 1024*256
    float* ys2 = ys1 + (size_t)NB * HDIM;       // 1024*256

    // sentinel-fill both exchange buffers (0xFFFFFFFF = NaN, never produced)
    hipMemsetAsync(ys1, 0xFF, 2 * (size_t)NB * HDIM * sizeof(float), stream);

    conv_kernel<<<NB, 256, 0, stream>>>(x, emb, X);

    gemm_bias<<<dim3(16, 16), 256, 0, stream>>>(X, w_ih0, b_ih0, b_hh0, G1, DIN);

    lstm_fused<<<256, 64, 0, stream>>>(G1, w_hh0, w_ih1, w_hh1, b_ih1, b_hh1,
                                       h0, c0, ys1, ys2, out);

    fc_kernel<<<NB / 4, 256, 0, stream>>>(ys2, fc_w, fc_b, out);
}

// Round 2
// 2807.569 us; speedup vs baseline: 1.2794x; 1.2794x over previous
//
#include <hip/hip_runtime.h>
#include <math.h>

// Problem constants
#define NB    1024      // batch rows == scan steps
#define SEQ   600
#define EDIM  300
#define HDIM  256
#define DIN   903       // 3*E + 3
#define GDIM  1024      // 4*H

#define SENT  0xFFFFFFFFu

// ---------------------------------------------------------------------------
// Kernel 1: conv (unchanged)
// ---------------------------------------------------------------------------
__global__ __launch_bounds__(256) void conv_kernel(const int* __restrict__ x,
                                                   const float* __restrict__ emb,
                                                   float* __restrict__ X) {
    const int row = blockIdx.x;
    const int tid = threadIdx.x;
    const int* xr = x + (size_t)row * SEQ;

    __shared__ float seg[3][EDIM];
    __shared__ float scnt[3];
    __shared__ float reds[6];
    __shared__ float coss[3];

    if (tid < 6) reds[tid] = 0.f;
    if (tid < 3) scnt[tid] = 0.f;
    __syncthreads();

    {
        int c0 = 0, c1 = 0, c2 = 0;
        for (int t = tid; t < 200; t += 256) {
            c0 += (xr[t]       != 0);
            c1 += (xr[200 + t] != 0);
            c2 += (xr[400 + t] != 0);
        }
        float f0 = (float)c0, f1 = (float)c1, f2 = (float)c2;
        #pragma unroll
        for (int m = 1; m < 64; m <<= 1) {
            f0 += __shfl_xor(f0, m);
            f1 += __shfl_xor(f1, m);
            f2 += __shfl_xor(f2, m);
        }
        if ((tid & 63) == 0) {
            atomicAdd(&scnt[0], f0);
            atomicAdd(&scnt[1], f1);
            atomicAdd(&scnt[2], f2);
        }
    }
    __syncthreads();

    const float inv0 = 1.f / scnt[0], inv1 = 1.f / scnt[1], inv2 = 1.f / scnt[2];

    for (int d = tid; d < EDIM; d += 256) {
        float a0 = 0.f, a1 = 0.f, a2 = 0.f;
        for (int t = 0; t < 200; t++) {
            a0 += emb[(size_t)xr[t]       * EDIM + d];
            a1 += emb[(size_t)xr[200 + t] * EDIM + d];
            a2 += emb[(size_t)xr[400 + t] * EDIM + d];
        }
        seg[0][d] = a0 * inv0;
        seg[1][d] = a1 * inv1;
        seg[2][d] = a2 * inv2;
    }
    __syncthreads();

    {
        float p0 = 0, p1 = 0, p2 = 0, p3 = 0, p4 = 0, p5 = 0;
        for (int d = tid; d < EDIM; d += 256) {
            float a = seg[0][d], b = seg[1][d], c = seg[2][d];
            p0 += a * a; p1 += b * b; p2 += c * c;
            p3 += a * b; p4 += b * c; p5 += a * c;
        }
        #pragma unroll
        for (int m = 1; m < 64; m <<= 1) {
            p0 += __shfl_xor(p0, m); p1 += __shfl_xor(p1, m);
            p2 += __shfl_xor(p2, m); p3 += __shfl_xor(p3, m);
            p4 += __shfl_xor(p4, m); p5 += __shfl_xor(p5, m);
        }
        if ((tid & 63) == 0) {
            atomicAdd(&reds[0], p0); atomicAdd(&reds[1], p1);
            atomicAdd(&reds[2], p2); atomicAdd(&reds[3], p3);
            atomicAdd(&reds[4], p4); atomicAdd(&reds[5], p5);
        }
    }
    __syncthreads();
    if (tid == 0) {
        float nt = fmaxf(sqrtf(reds[0]), 1e-8f);
        float nu = fmaxf(sqrtf(reds[1]), 1e-8f);
        float nj = fmaxf(sqrtf(reds[2]), 1e-8f);
        coss[0] = reds[3] / (nt * nu);
        coss[1] = reds[4] / (nu * nj);
        coss[2] = reds[5] / (nt * nj);
    }
    __syncthreads();

    float* Xr = X + (size_t)row * DIN;
    for (int col = tid; col < DIN; col += 256) {
        float v;
        if      (col < 300)  v = seg[0][col];
        else if (col == 300) v = coss[0];
        else if (col < 601)  v = seg[1][col - 301];
        else if (col == 601) v = coss[1];
        else if (col < 902)  v = seg[2][col - 602];
        else                 v = coss[2];
        Xr[col] = v;
    }
}

// ---------------------------------------------------------------------------
// Kernel 2: GEMM (unchanged)
// ---------------------------------------------------------------------------
__global__ __launch_bounds__(256) void gemm_bias(const float* __restrict__ A,
                                                 const float* __restrict__ Bm,
                                                 const float* __restrict__ bias1,
                                                 const float* __restrict__ bias2,
                                                 float* __restrict__ C, int K) {
    __shared__ float As[16][68];
    __shared__ float Bs[16][68];
    const int tid = threadIdx.x;
    const int tx = tid & 15, ty = tid >> 4;
    const int m0 = blockIdx.y * 64, n0 = blockIdx.x * 64;

    float acc[4][4] = {};
    for (int k0 = 0; k0 < K; k0 += 16) {
        #pragma unroll
        for (int i = 0; i < 4; i++) {
            int e  = tid + i * 256;
            int rr = e >> 4, kk = e & 15;
            int k  = k0 + kk;
            As[kk][rr] = (k < K) ? A[(size_t)(m0 + rr) * K + k] : 0.f;
            Bs[kk][rr] = (k < K) ? Bm[(size_t)(n0 + rr) * K + k] : 0.f;
        }
        __syncthreads();
        #pragma unroll
        for (int kk = 0; kk < 16; kk++) {
            float a[4], b[4];
            #pragma unroll
            for (int i = 0; i < 4; i++) { a[i] = As[kk][ty * 4 + i]; b[i] = Bs[kk][tx * 4 + i]; }
            #pragma unroll
            for (int i = 0; i < 4; i++)
                #pragma unroll
                for (int j = 0; j < 4; j++)
                    acc[i][j] += a[i] * b[j];
        }
        __syncthreads();
    }
    #pragma unroll
    for (int i = 0; i < 4; i++) {
        int m = m0 + ty * 4 + i;
        #pragma unroll
        for (int j = 0; j < 4; j++) {
            int n = n0 + tx * 4 + j;
            C[(size_t)m * GDIM + n] = acc[i][j] + bias1[n] + bias2[n];
        }
    }
}

// ---------------------------------------------------------------------------
// Kernel 3: fused 2-layer LSTM, contention-free replica mailboxes.
// Grid: 12 WGs x 1024 threads.
//   WG 0..3   = L1, WG w1 owns elems [w1*64, +64): 4 lanes/row x 64 cols.
//   WG 4..11  = L2, WG w2 owns elems [w2*32, +32): 8 lanes/row x 32 cols.
// Mail slots are READER-PRIVATE (one writer wave, one reader WG per line):
//   mailA[k][t][256]  : h1(t) for L1 consumer WG k        (k=0..3)
//   mailX[m][t][256]  : h1(t) as x-input for L2 WG m      (m=0..7)
//   mailB[k][t][256]  : h2(t) for L2 consumer WG k        (k=0..7)
// Only threads 0..511 poll (1 dword each, coalesced); h is broadcast to the
// WG through double-buffered LDS behind ONE __syncthreads per step. Own-slice
// h skips the mailbox (written directly into next step's LDS buffer).
// LDS layout [4][68] / [8][36] staggers the q-blocks across banks so the
// float4 broadcast reads are conflict-free.
// ---------------------------------------------------------------------------
__global__ __launch_bounds__(1024) void lstm_fused(
    const float* __restrict__ G1,
    const float* __restrict__ Whh0,
    const float* __restrict__ Wih1,
    const float* __restrict__ Whh1,
    const float* __restrict__ b_ih1,
    const float* __restrict__ b_hh1,
    const float* __restrict__ h0,
    const float* __restrict__ c0,
    float* mailA, float* mailX, float* mailB,
    float* ys2, float* out)
{
    const int tid = threadIdx.x;
    const int v   = tid >> 6;        // wave 0..15
    const int l   = tid & 63;        // lane
    const int bid = blockIdx.x;

    if (bid < 4) {
        // ------------------------------ Layer 1 ------------------------------
        const int w1 = bid;
        const int k  = l >> 4;           // elem within wave (0..3)
        const int g  = (l >> 2) & 3;     // gate
        const int q  = l & 3;            // col quarter (64 cols each)
        const int eg  = w1 * 64 + 4 * v + k;
        const int row = g * 256 + eg;

        __shared__ __align__(16) float hl[2][4][68];   // +4 pad staggers banks

        float4 wh[16];
        #pragma unroll
        for (int j = 0; j < 16; j++)
            wh[j] = *(const float4*)&Whh0[(size_t)row * HDIM + q * 64 + j * 4];

        float c = c0[eg];

        for (int t = 0; t < NB; t++) {
            const int nb = t & 1;
            float gv = G1[(size_t)t * GDIM + row];     // issued early, used late

            if (t == 0) {
                if (tid < 256) hl[0][tid >> 6][tid & 63] = h0[tid];
            } else if (tid < 256 && (tid >> 6) != w1) {
                const unsigned* p = (const unsigned*)
                    (mailA + ((size_t)w1 * NB + (t - 1)) * HDIM + tid);
                unsigned u; int gd = 0;
                do { u = __hip_atomic_load(p, __ATOMIC_RELAXED, __HIP_MEMORY_SCOPE_AGENT); }
                while (u == SENT && ++gd < (1 << 24));
                hl[nb][tid >> 6][tid & 63] = __uint_as_float(u);
            }
            __syncthreads();

            float acc = 0.f;
            #pragma unroll
            for (int j = 0; j < 16; j++) {
                float4 hv = *(const float4*)&hl[nb][q][j * 4];
                float4 wv = wh[j];
                acc += hv.x * wv.x + hv.y * wv.y + hv.z * wv.z + hv.w * wv.w;
            }
            acc += __shfl_xor(acc, 1);
            acc += __shfl_xor(acc, 2);
            acc += gv;

            const int base = l & 48;
            float gi = __shfl(acc, base);
            float gf = __shfl(acc, base + 4);
            float gg = __shfl(acc, base + 8);
            float go = __shfl(acc, base + 12);

            float ig = 1.f / (1.f + expf(-gi));
            float fg = 1.f / (1.f + expf(-gf));
            float og = 1.f / (1.f + expf(-go));
            c = fg * c + ig * tanhf(gg);
            float h = og * tanhf(c);

            float h4 = __shfl(h, (l & 3) * 16);
            float c4 = __shfl(c, (l & 3) * 16);
            if (l < 4) {
                const int el = 4 * v + l;
                const int e  = w1 * 64 + el;
                hl[nb ^ 1][w1][el] = h4;               // own slice, next step
                const unsigned hb = __float_as_uint(h4);
                #pragma unroll
                for (int kk = 0; kk < 4; kk++)
                    if (kk != w1)
                        __hip_atomic_store((unsigned*)(mailA + ((size_t)kk * NB + t) * HDIM + e),
                                           hb, __ATOMIC_RELAXED, __HIP_MEMORY_SCOPE_AGENT);
                #pragma unroll
                for (int m = 0; m < 8; m++)
                    __hip_atomic_store((unsigned*)(mailX + ((size_t)m * NB + t) * HDIM + e),
                                       hb, __ATOMIC_RELAXED, __HIP_MEMORY_SCOPE_AGENT);
                if (t == NB - 1) { out[1024 + e] = h4; out[1536 + e] = c4; }
            }
        }
    } else {
        // ------------------------------ Layer 2 ------------------------------
        const int w2 = bid - 4;
        const int k  = l >> 5;           // elem within wave (0..1)
        const int g  = (l >> 3) & 3;     // gate
        const int q  = l & 7;            // col eighth (32 cols each)
        const int eg  = w2 * 32 + 2 * v + k;
        const int row = g * 256 + eg;

        __shared__ __align__(16) float hl[2][8][36];
        __shared__ __align__(16) float xl[2][8][36];

        float4 wh[8], wi[8];
        #pragma unroll
        for (int j = 0; j < 8; j++) {
            wh[j] = *(const float4*)&Whh1[(size_t)row * HDIM + q * 32 + j * 4];
            wi[j] = *(const float4*)&Wih1[(size_t)row * HDIM + q * 32 + j * 4];
        }
        const float bsum = b_ih1[row] + b_hh1[row];

        float c = c0[HDIM + eg];

        for (int t = 0; t < NB; t++) {
            const int nb = t & 1;

            if (tid < 256) {
                // waves 0..3: poll x = ys1[t] from private slot
                const unsigned* p = (const unsigned*)
                    (mailX + ((size_t)w2 * NB + t) * HDIM + tid);
                unsigned u; int gd = 0;
                do { u = __hip_atomic_load(p, __ATOMIC_RELAXED, __HIP_MEMORY_SCOPE_AGENT); }
                while (u == SENT && ++gd < (1 << 24));
                xl[nb][tid >> 5][tid & 31] = __uint_as_float(u);
            } else if (tid < 512) {
                // waves 4..7: fill h2(t-1)
                const int j = tid - 256;
                if (t == 0) {
                    hl[0][j >> 5][j & 31] = h0[HDIM + j];
                } else if ((j >> 5) != w2) {
                    const unsigned* p = (const unsigned*)
                        (mailB + ((size_t)w2 * NB + (t - 1)) * HDIM + j);
                    unsigned u; int gd = 0;
                    do { u = __hip_atomic_load(p, __ATOMIC_RELAXED, __HIP_MEMORY_SCOPE_AGENT); }
                    while (u == SENT && ++gd < (1 << 24));
                    hl[nb][j >> 5][j & 31] = __uint_as_float(u);
                }
            }
            __syncthreads();

            float acc = 0.f;
            #pragma unroll
            for (int j = 0; j < 8; j++) {
                float4 hv = *(const float4*)&hl[nb][q][j * 4];
                float4 wv = wh[j];
                acc += hv.x * wv.x + hv.y * wv.y + hv.z * wv.z + hv.w * wv.w;
                float4 xv = *(const float4*)&xl[nb][q][j * 4];
                float4 wu = wi[j];
                acc += xv.x * wu.x + xv.y * wu.y + xv.z * wu.z + xv.w * wu.w;
            }
            acc += __shfl_xor(acc, 1);
            acc += __shfl_xor(acc, 2);
            acc += __shfl_xor(acc, 4);
            acc += bsum;

            const int base = l & 32;
            float gi = __shfl(acc, base);
            float gf = __shfl(acc, base + 8);
            float gg = __shfl(acc, base + 16);
            float go = __shfl(acc, base + 24);

            float ig = 1.f / (1.f + expf(-gi));
            float fg = 1.f / (1.f + expf(-gf));
            float og = 1.f / (1.f + expf(-go));
            c = fg * c + ig * tanhf(gg);
            float h = og * tanhf(c);

            float h2 = __shfl(h, (l & 1) * 32);
            float c2 = __shfl(c, (l & 1) * 32);
            if (l < 2) {
                const int el = 2 * v + l;
                const int e  = w2 * 32 + el;
                hl[nb ^ 1][w2][el] = h2;               // own slice, next step
                const unsigned hb = __float_as_uint(h2);
                #pragma unroll
                for (int kk = 0; kk < 8; kk++)
                    if (kk != w2)
                        __hip_atomic_store((unsigned*)(mailB + ((size_t)kk * NB + t) * HDIM + e),
                                           hb, __ATOMIC_RELAXED, __HIP_MEMORY_SCOPE_AGENT);
                ys2[(size_t)t * HDIM + e] = h2;        // canonical, for fc
                if (t == NB - 1) { out[1024 + HDIM + e] = h2; out[1536 + HDIM + e] = c2; }
            }
        }
    }
}

// ---------------------------------------------------------------------------
// Kernel 4: fc head (unchanged)
// ---------------------------------------------------------------------------
__global__ __launch_bounds__(256) void fc_kernel(const float* __restrict__ ys2,
                                                 const float* __restrict__ fc_w,
                                                 const float* __restrict__ fc_b,
                                                 float* __restrict__ out) {
    const int row  = blockIdx.x * 4 + (threadIdx.x >> 6);
    const int lane = threadIdx.x & 63;
    float4 y = ((const float4*)(ys2 + (size_t)row * HDIM))[lane];
    float4 wv = ((const float4*)fc_w)[lane];
    float d = y.x * wv.x + y.y * wv.y + y.z * wv.z + y.w * wv.w;
    #pragma unroll
    for (int m = 1; m < 64; m <<= 1) d += __shfl_xor(d, m);
    if (lane == 0) out[row] = 1.f / (1.f + expf(-(d + fc_b[0])));
}

// ---------------------------------------------------------------------------
extern "C" void kernel_launch(void* const* d_in, const int* in_sizes, int n_in,
                              void* d_out, int out_size, void* d_ws, size_t ws_size,
                              hipStream_t stream) {
    const int*   x     = (const int*)  d_in[0];
    const float* h0    = (const float*)d_in[1];
    const float* c0    = (const float*)d_in[2];
    const float* emb   = (const float*)d_in[3];
    const float* w_ih0 = (const float*)d_in[4];
    const float* w_hh0 = (const float*)d_in[5];
    const float* b_ih0 = (const float*)d_in[6];
    const float* b_hh0 = (const float*)d_in[7];
    const float* w_ih1 = (const float*)d_in[8];
    const float* w_hh1 = (const float*)d_in[9];
    const float* b_ih1 = (const float*)d_in[10];
    const float* b_hh1 = (const float*)d_in[11];
    const float* fc_w  = (const float*)d_in[12];
    const float* fc_b  = (const float*)d_in[13];
    float* out = (float*)d_out;

    // workspace layout (floats), ~30 MB total
    float* X     = (float*)d_ws;                    // 1024*903
    float* G1    = X     + (size_t)NB * DIN;        // 1024*1024
    float* ys2   = G1    + (size_t)NB * GDIM;       // 1024*256
    float* mailA = ys2   + (size_t)NB * HDIM;       // 4 *1024*256
    float* mailX = mailA + (size_t)4 * NB * HDIM;   // 8 *1024*256
    float* mailB = mailX + (size_t)8 * NB * HDIM;   // 8 *1024*256

    // sentinel-fill all mail slots (0xFFFFFFFF = NaN, never produced): 20 MB
    hipMemsetAsync(mailA, 0xFF, (size_t)(4 + 8 + 8) * NB * HDIM * sizeof(float), stream);

    conv_kernel<<<NB, 256, 0, stream>>>(x, emb, X);

    gemm_bias<<<dim3(16, 16), 256, 0, stream>>>(X, w_ih0, b_ih0, b_hh0, G1, DIN);

    lstm_fused<<<12, 1024, 0, stream>>>(G1, w_hh0, w_ih1, w_hh1, b_ih1, b_hh1,
                                        h0, c0, mailA, mailX, mailB, ys2, out);

    fc_kernel<<<NB / 4, 256, 0, stream>>>(ys2, fc_w, fc_b, out);
}

// Round 3
// 2204.914 us; speedup vs baseline: 1.6291x; 1.2733x over previous
//
#include <hip/hip_runtime.h>
#include <math.h>

// Problem constants
#define NB    1024      // batch rows == scan steps
#define SEQ   600
#define EDIM  300
#define HDIM  256
#define DIN   903       // 3*E + 3
#define GDIM  1024      // 4*H

#define SENT  0xFFFFFFFFu

// ---------------------------------------------------------------------------
// fast transcendentals: v_exp_f32 / v_rcp_f32 (≤2 ulp, fine vs 3e-5 tolerance)
// ---------------------------------------------------------------------------
__device__ __forceinline__ float fsig(float x) {
    return __builtin_amdgcn_rcpf(1.f + __builtin_amdgcn_exp2f(x * -1.44269504f));
}
__device__ __forceinline__ float ftanh(float x) {
    // tanh(x) = 1 - 2/(exp2(2x*log2e)+1)
    return 1.f - 2.f * __builtin_amdgcn_rcpf(1.f + __builtin_amdgcn_exp2f(x * 2.88539008f));
}

// 16-lane rotation-reduce on the VALU pipe (no LDS traffic).
// row_ror:N DPP ctrl = 0x120|N. After ror8,ror4,ror2,ror1 every lane of each
// 16-lane row holds the full 16-lane sum.
__device__ __forceinline__ float row16_sum(float x) {
    x += __int_as_float(__builtin_amdgcn_update_dpp(0, __float_as_int(x), 0x128, 0xf, 0xf, true));
    x += __int_as_float(__builtin_amdgcn_update_dpp(0, __float_as_int(x), 0x124, 0xf, 0xf, true));
    x += __int_as_float(__builtin_amdgcn_update_dpp(0, __float_as_int(x), 0x122, 0xf, 0xf, true));
    x += __int_as_float(__builtin_amdgcn_update_dpp(0, __float_as_int(x), 0x121, 0xf, 0xf, true));
    return x;
}

// Barrier that waits only LDS ops (lgkmcnt), NOT the in-flight mailbox
// global stores (vmcnt) — __syncthreads would drain those every step.
__device__ __forceinline__ void lds_barrier() {
    asm volatile("s_waitcnt lgkmcnt(0)" ::: "memory");
    __builtin_amdgcn_s_barrier();
}

__device__ __forceinline__ float poll_f(const float* p) {
    const unsigned* up = (const unsigned*)p;
    unsigned u; int gd = 0;
    do { u = __hip_atomic_load(up, __ATOMIC_RELAXED, __HIP_MEMORY_SCOPE_AGENT); }
    while (u == SENT && ++gd < (1 << 24));
    return __uint_as_float(u);
}
__device__ __forceinline__ void st_f(float* p, float v) {
    __hip_atomic_store(p, v, __ATOMIC_RELAXED, __HIP_MEMORY_SCOPE_AGENT);
}

// ---------------------------------------------------------------------------
// Kernel 1: conv (unchanged)
// ---------------------------------------------------------------------------
__global__ __launch_bounds__(256) void conv_kernel(const int* __restrict__ x,
                                                   const float* __restrict__ emb,
                                                   float* __restrict__ X) {
    const int row = blockIdx.x;
    const int tid = threadIdx.x;
    const int* xr = x + (size_t)row * SEQ;

    __shared__ float seg[3][EDIM];
    __shared__ float scnt[3];
    __shared__ float reds[6];
    __shared__ float coss[3];

    if (tid < 6) reds[tid] = 0.f;
    if (tid < 3) scnt[tid] = 0.f;
    __syncthreads();

    {
        int c0 = 0, c1 = 0, c2 = 0;
        for (int t = tid; t < 200; t += 256) {
            c0 += (xr[t]       != 0);
            c1 += (xr[200 + t] != 0);
            c2 += (xr[400 + t] != 0);
        }
        float f0 = (float)c0, f1 = (float)c1, f2 = (float)c2;
        #pragma unroll
        for (int m = 1; m < 64; m <<= 1) {
            f0 += __shfl_xor(f0, m);
            f1 += __shfl_xor(f1, m);
            f2 += __shfl_xor(f2, m);
        }
        if ((tid & 63) == 0) {
            atomicAdd(&scnt[0], f0);
            atomicAdd(&scnt[1], f1);
            atomicAdd(&scnt[2], f2);
        }
    }
    __syncthreads();

    const float inv0 = 1.f / scnt[0], inv1 = 1.f / scnt[1], inv2 = 1.f / scnt[2];

    for (int d = tid; d < EDIM; d += 256) {
        float a0 = 0.f, a1 = 0.f, a2 = 0.f;
        for (int t = 0; t < 200; t++) {
            a0 += emb[(size_t)xr[t]       * EDIM + d];
            a1 += emb[(size_t)xr[200 + t] * EDIM + d];
            a2 += emb[(size_t)xr[400 + t] * EDIM + d];
        }
        seg[0][d] = a0 * inv0;
        seg[1][d] = a1 * inv1;
        seg[2][d] = a2 * inv2;
    }
    __syncthreads();

    {
        float p0 = 0, p1 = 0, p2 = 0, p3 = 0, p4 = 0, p5 = 0;
        for (int d = tid; d < EDIM; d += 256) {
            float a = seg[0][d], b = seg[1][d], c = seg[2][d];
            p0 += a * a; p1 += b * b; p2 += c * c;
            p3 += a * b; p4 += b * c; p5 += a * c;
        }
        #pragma unroll
        for (int m = 1; m < 64; m <<= 1) {
            p0 += __shfl_xor(p0, m); p1 += __shfl_xor(p1, m);
            p2 += __shfl_xor(p2, m); p3 += __shfl_xor(p3, m);
            p4 += __shfl_xor(p4, m); p5 += __shfl_xor(p5, m);
        }
        if ((tid & 63) == 0) {
            atomicAdd(&reds[0], p0); atomicAdd(&reds[1], p1);
            atomicAdd(&reds[2], p2); atomicAdd(&reds[3], p3);
            atomicAdd(&reds[4], p4); atomicAdd(&reds[5], p5);
        }
    }
    __syncthreads();
    if (tid == 0) {
        float nt = fmaxf(sqrtf(reds[0]), 1e-8f);
        float nu = fmaxf(sqrtf(reds[1]), 1e-8f);
        float nj = fmaxf(sqrtf(reds[2]), 1e-8f);
        coss[0] = reds[3] / (nt * nu);
        coss[1] = reds[4] / (nu * nj);
        coss[2] = reds[5] / (nt * nj);
    }
    __syncthreads();

    float* Xr = X + (size_t)row * DIN;
    for (int col = tid; col < DIN; col += 256) {
        float v;
        if      (col < 300)  v = seg[0][col];
        else if (col == 300) v = coss[0];
        else if (col < 601)  v = seg[1][col - 301];
        else if (col == 601) v = coss[1];
        else if (col < 902)  v = seg[2][col - 602];
        else                 v = coss[2];
        Xr[col] = v;
    }
}

// ---------------------------------------------------------------------------
// Kernel 2: GEMM (unchanged) — G1 = X @ Wih0^T + b_ih0 + b_hh0
// ---------------------------------------------------------------------------
__global__ __launch_bounds__(256) void gemm_bias(const float* __restrict__ A,
                                                 const float* __restrict__ Bm,
                                                 const float* __restrict__ bias1,
                                                 const float* __restrict__ bias2,
                                                 float* __restrict__ C, int K) {
    __shared__ float As[16][68];
    __shared__ float Bs[16][68];
    const int tid = threadIdx.x;
    const int tx = tid & 15, ty = tid >> 4;
    const int m0 = blockIdx.y * 64, n0 = blockIdx.x * 64;

    float acc[4][4] = {};
    for (int k0 = 0; k0 < K; k0 += 16) {
        #pragma unroll
        for (int i = 0; i < 4; i++) {
            int e  = tid + i * 256;
            int rr = e >> 4, kk = e & 15;
            int k  = k0 + kk;
            As[kk][rr] = (k < K) ? A[(size_t)(m0 + rr) * K + k] : 0.f;
            Bs[kk][rr] = (k < K) ? Bm[(size_t)(n0 + rr) * K + k] : 0.f;
        }
        __syncthreads();
        #pragma unroll
        for (int kk = 0; kk < 16; kk++) {
            float a[4], b[4];
            #pragma unroll
            for (int i = 0; i < 4; i++) { a[i] = As[kk][ty * 4 + i]; b[i] = Bs[kk][tx * 4 + i]; }
            #pragma unroll
            for (int i = 0; i < 4; i++)
                #pragma unroll
                for (int j = 0; j < 4; j++)
                    acc[i][j] += a[i] * b[j];
        }
        __syncthreads();
    }
    #pragma unroll
    for (int i = 0; i < 4; i++) {
        int m = m0 + ty * 4 + i;
        #pragma unroll
        for (int j = 0; j < 4; j++) {
            int n = n0 + tx * 4 + j;
            C[(size_t)m * GDIM + n] = acc[i][j] + bias1[n] + bias2[n];
        }
    }
}

// ---------------------------------------------------------------------------
// Kernel 3: fused 2-layer LSTM, (4,16) mapping + DPP reduce + raw barrier.
// Grid: 24 WGs x 512 threads.
//   bid 0..7   = L1 recurrence, WG m owns elems [m*32,+32)
//   bid 8..15  = L2 recurrence, WG m owns elems [m*32,+32)
//   bid 16..23 = X-stage n: P2 rows (Wih1·ys1[t] + biases) for elems [n*32,+32)
// Each 16-lane group owns ONE element: lanes q=0..15 hold cols q*16..+15 of
// all 4 gate rows (i,f,g,o) -> 4 ds_read_b128/wave/step, gates land in-lane
// after 4 DPP rotation-reduce stages, nonlinearity computed redundantly x16.
// Mailboxes (write-once, 0xFFFFFFFF sentinel, relaxed agent atomics):
//   mailA[8][t][256]  h1 replicas, reader-private per L1 WG
//   mailX[4][t][256]  h1 replicas for X-stage (2 X-WGs share 1 replica)
//   mailB[8][t][256]  h2 replicas, reader-private per L2 WG
//   mailP[8][t][128]  P2 row partials, X-WG n -> L2 WG n (single writer/reader)
// ---------------------------------------------------------------------------
__global__ __launch_bounds__(512) void lstm_fused(
    const float* __restrict__ G1,
    const float* __restrict__ Whh0,
    const float* __restrict__ Wih1,
    const float* __restrict__ Whh1,
    const float* __restrict__ b_ih1,
    const float* __restrict__ b_hh1,
    const float* __restrict__ h0,
    const float* __restrict__ c0,
    float* mailA, float* mailX, float* mailB, float* mailP,
    float* ys2, float* out)
{
    const int tid = threadIdx.x;
    const int bid = blockIdx.x;
    const int l   = tid & 63;
    const int v   = tid >> 6;          // wave 0..7
    const int k   = l >> 4;            // elem within wave (0..3)
    const int q   = l & 15;            // 16-col chunk / role selector

    // h broadcast, double-buffered. [16][20] layout: 16B-aligned rows (80B),
    // bank starts q*20 mod 32 -> at most 2-way conflicts (free).
    __shared__ __align__(16) float hb[2][16][20];

    if (bid < 16) {
        // ---------------- recurrence WG (L=0: layer1, L=1: layer2) ----------
        const int  L = bid >> 3;
        const int  m = bid & 7;
        const int  e = m * 32 + 4 * v + k;      // owned element 0..255
        const int  eloc = e & 31;
        const float* Wh = L ? Whh1 : Whh0;
        float* mailH = L ? mailB : mailA;

        // weights: rows g*256+e, cols q*16..+15  (64 VGPRs)
        float4 w[4][4];
        #pragma unroll
        for (int g = 0; g < 4; g++)
            #pragma unroll
            for (int j = 0; j < 4; j++)
                w[g][j] = *(const float4*)&Wh[(size_t)(g * 256 + e) * HDIM + q * 16 + j * 4];

        float c = c0[L * HDIM + e];

        for (int t = 0; t < NB; t++) {
            const int nb = t & 1;

            // early G-term issue (one gate row per lane, q<4 only)
            float gq = 0.f;
            unsigned gu = 0;
            const unsigned* gp = nullptr;
            if (q < 4) {
                if (L == 0) {
                    gq = G1[(size_t)t * GDIM + q * 256 + e];
                } else {
                    gp = (const unsigned*)(mailP + ((size_t)m * NB + t) * 128 + q * 32 + eloc);
                    gu = __hip_atomic_load(gp, __ATOMIC_RELAXED, __HIP_MEMORY_SCOPE_AGENT);
                }
            }

            // fill h broadcast (own 32-elem slice was written at t-1 epilogue)
            if (tid < HDIM) {
                if (t == 0) {
                    hb[0][tid >> 4][tid & 15] = h0[L * HDIM + tid];
                } else if ((tid >> 5) != m) {
                    hb[nb][tid >> 4][tid & 15] =
                        poll_f(mailH + ((size_t)m * NB + (t - 1)) * HDIM + tid);
                }
            }
            lds_barrier();

            // matvec: 4 gate rows x 16 cols, h via 4 ds_read_b128
            float a0 = 0.f, a1 = 0.f, a2 = 0.f, a3 = 0.f;
            #pragma unroll
            for (int j = 0; j < 4; j++) {
                float4 hv = *(const float4*)&hb[nb][q][j * 4];
                float4 w0 = w[0][j], w1 = w[1][j], w2 = w[2][j], w3 = w[3][j];
                a0 += hv.x * w0.x + hv.y * w0.y + hv.z * w0.z + hv.w * w0.w;
                a1 += hv.x * w1.x + hv.y * w1.y + hv.z * w1.z + hv.w * w1.w;
                a2 += hv.x * w2.x + hv.y * w2.y + hv.z * w2.z + hv.w * w2.w;
                a3 += hv.x * w3.x + hv.y * w3.y + hv.z * w3.z + hv.w * w3.w;
            }

            // add G-term once per row (lane q carries row g=q)
            if (q < 4) {
                if (L == 1) {
                    int gd = 0;
                    while (gu == SENT && ++gd < (1 << 24))
                        gu = __hip_atomic_load(gp, __ATOMIC_RELAXED, __HIP_MEMORY_SCOPE_AGENT);
                    gq = __uint_as_float(gu);
                }
                if      (q == 0) a0 += gq;
                else if (q == 1) a1 += gq;
                else if (q == 2) a2 += gq;
                else             a3 += gq;
            }

            // 16-lane DPP reductions (VALU pipe): all lanes get all 4 gates
            a0 = row16_sum(a0); a1 = row16_sum(a1);
            a2 = row16_sum(a2); a3 = row16_sum(a3);

            float ig = fsig(a0), fg = fsig(a1), og = fsig(a3);
            c = fg * c + ig * ftanh(a2);
            float h = og * ftanh(c);

            // publish (roles spread across the 16 redundant lanes)
            if (q == 4) hb[nb ^ 1][e >> 4][e & 15] = h;       // own slice, t+1
            if (q == 0) {
                #pragma unroll
                for (int r = 0; r < 4; r++)
                    if (r != m) st_f(mailH + ((size_t)r * NB + t) * HDIM + e, h);
            }
            if (q == 1) {
                #pragma unroll
                for (int r = 4; r < 8; r++)
                    if (r != m) st_f(mailH + ((size_t)r * NB + t) * HDIM + e, h);
            }
            if (L == 0) {
                if (q == 2) {
                    st_f(mailX + ((size_t)0 * NB + t) * HDIM + e, h);
                    st_f(mailX + ((size_t)1 * NB + t) * HDIM + e, h);
                }
                if (q == 3) {
                    st_f(mailX + ((size_t)2 * NB + t) * HDIM + e, h);
                    st_f(mailX + ((size_t)3 * NB + t) * HDIM + e, h);
                }
            } else {
                if (q == 2) ys2[(size_t)t * HDIM + e] = h;
            }
            if (t == NB - 1 && q == 5) {
                out[1024 + L * HDIM + e] = h;    // hn
                out[1536 + L * HDIM + e] = c;    // cn
            }
        }
    } else {
        // ---------------- X-stage: P2[t] = Wih1·ys1[t] + b_ih1 + b_hh1 ------
        const int n = bid - 16;
        const int e = n * 32 + 4 * v + k;
        const int eloc = e & 31;
        const float* xsrc = mailX + (size_t)(n >> 1) * NB * HDIM;

        float4 w[4][4];
        #pragma unroll
        for (int g = 0; g < 4; g++)
            #pragma unroll
            for (int j = 0; j < 4; j++)
                w[g][j] = *(const float4*)&Wih1[(size_t)(g * 256 + e) * HDIM + q * 16 + j * 4];

        float bsum = 0.f;
        if (q < 4) bsum = b_ih1[q * 256 + e] + b_hh1[q * 256 + e];

        for (int t = 0; t < NB; t++) {
            const int nb = t & 1;
            if (tid < HDIM)
                hb[nb][tid >> 4][tid & 15] = poll_f(xsrc + (size_t)t * HDIM + tid);
            lds_barrier();

            float a0 = 0.f, a1 = 0.f, a2 = 0.f, a3 = 0.f;
            #pragma unroll
            for (int j = 0; j < 4; j++) {
                float4 hv = *(const float4*)&hb[nb][q][j * 4];
                float4 w0 = w[0][j], w1 = w[1][j], w2 = w[2][j], w3 = w[3][j];
                a0 += hv.x * w0.x + hv.y * w0.y + hv.z * w0.z + hv.w * w0.w;
                a1 += hv.x * w1.x + hv.y * w1.y + hv.z * w1.z + hv.w * w1.w;
                a2 += hv.x * w2.x + hv.y * w2.y + hv.z * w2.z + hv.w * w2.w;
                a3 += hv.x * w3.x + hv.y * w3.y + hv.z * w3.z + hv.w * w3.w;
            }
            a0 = row16_sum(a0); a1 = row16_sum(a1);
            a2 = row16_sum(a2); a3 = row16_sum(a3);

            if (q < 4) {
                float pv = (q == 0 ? a0 : q == 1 ? a1 : q == 2 ? a2 : a3) + bsum;
                st_f(mailP + ((size_t)n * NB + t) * 128 + q * 32 + eloc, pv);
            }
        }
    }
}

// ---------------------------------------------------------------------------
// Kernel 4: fc head (unchanged)
// ---------------------------------------------------------------------------
__global__ __launch_bounds__(256) void fc_kernel(const float* __restrict__ ys2,
                                                 const float* __restrict__ fc_w,
                                                 const float* __restrict__ fc_b,
                                                 float* __restrict__ out) {
    const int row  = blockIdx.x * 4 + (threadIdx.x >> 6);
    const int lane = threadIdx.x & 63;
    float4 y = ((const float4*)(ys2 + (size_t)row * HDIM))[lane];
    float4 wv = ((const float4*)fc_w)[lane];
    float d = y.x * wv.x + y.y * wv.y + y.z * wv.z + y.w * wv.w;
    #pragma unroll
    for (int m = 1; m < 64; m <<= 1) d += __shfl_xor(d, m);
    if (lane == 0) out[row] = 1.f / (1.f + expf(-(d + fc_b[0])));
}

// ---------------------------------------------------------------------------
extern "C" void kernel_launch(void* const* d_in, const int* in_sizes, int n_in,
                              void* d_out, int out_size, void* d_ws, size_t ws_size,
                              hipStream_t stream) {
    const int*   x     = (const int*)  d_in[0];
    const float* h0    = (const float*)d_in[1];
    const float* c0    = (const float*)d_in[2];
    const float* emb   = (const float*)d_in[3];
    const float* w_ih0 = (const float*)d_in[4];
    const float* w_hh0 = (const float*)d_in[5];
    const float* b_ih0 = (const float*)d_in[6];
    const float* b_hh0 = (const float*)d_in[7];
    const float* w_ih1 = (const float*)d_in[8];
    const float* w_hh1 = (const float*)d_in[9];
    const float* b_ih1 = (const float*)d_in[10];
    const float* b_hh1 = (const float*)d_in[11];
    const float* fc_w  = (const float*)d_in[12];
    const float* fc_b  = (const float*)d_in[13];
    float* out = (float*)d_out;

    // workspace layout (floats), ~30.4 MB total.
    // mail region first; conv's X buffer ALIASES its start (X is dead after
    // the gemm, and the mail memset runs after the gemm).
    float* mail  = (float*)d_ws;
    float* mailA = mail;                               // 8 *NB*HDIM  (8 MB)
    float* mailX = mailA + (size_t)8 * NB * HDIM;      // 4 *NB*HDIM  (4 MB)
    float* mailB = mailX + (size_t)4 * NB * HDIM;      // 8 *NB*HDIM  (8 MB)
    float* mailP = mailB + (size_t)8 * NB * HDIM;      // 8 *NB*128   (4 MB)
    float* G1    = mailP + (size_t)8 * NB * 128;       // NB*GDIM     (4 MB)
    float* ys2   = G1    + (size_t)NB * GDIM;          // NB*HDIM     (1 MB)
    float* X     = mail;                               // 1024*903, aliased

    conv_kernel<<<NB, 256, 0, stream>>>(x, emb, X);

    gemm_bias<<<dim3(16, 16), 256, 0, stream>>>(X, w_ih0, b_ih0, b_hh0, G1, DIN);

    // sentinel-fill all mail slots AFTER gemm (X is dead now): 24 MB
    hipMemsetAsync(mail, 0xFF, (size_t)(8 + 4 + 8) * NB * HDIM * sizeof(float)
                               + (size_t)8 * NB * 128 * sizeof(float), stream);

    lstm_fused<<<24, 512, 0, stream>>>(G1, w_hh0, w_ih1, w_hh1, b_ih1, b_hh1,
                                       h0, c0, mailA, mailX, mailB, mailP,
                                       ys2, out);

    fc_kernel<<<NB / 4, 256, 0, stream>>>(ys2, fc_w, fc_b, out);
}